// Round 3
// baseline (14569.070 us; speedup 1.0000x reference)
//
#include <hip/hip_runtime.h>

// ---------------------------------------------------------------------------
// SDKT model: embeddings -> biLSTM encoder -> enc LSTM -> dec LSTM -> MLP head
// B=256, T=256, H=512, G=2048, enc/dec input = 288, enc2 input = 1024.
// GEMMs bf16 MFMA (f32 accum). Recurrences run as PERSISTENT cooperative
// kernels (one per CH-step chunk): w_hh register-resident (128 VGPR/lane),
// c-state register-resident, per-step scoped 8-block barrier via agent-scope
// atomics + threadfence (cross-XCD safe). Activations TIME-MAJOR [T][B][*].
// ---------------------------------------------------------------------------

using u16 = unsigned short;
using u32 = unsigned int;
typedef float f32x4 __attribute__((ext_vector_type(4)));
typedef __bf16 bf16x8 __attribute__((ext_vector_type(8)));

__device__ __forceinline__ u16 f2bf(float f) {
  u32 u = __float_as_uint(f);
  u = (u + 0x7FFFu + ((u >> 16) & 1u)) >> 16;  // RNE
  return (u16)u;
}
__device__ __forceinline__ float bf2f(u16 h) { return __uint_as_float(((u32)h) << 16); }
__device__ __forceinline__ float sigm(float x) { return 1.f / (1.f + __expf(-x)); }
__device__ __forceinline__ float tnh(float x) {
  float a = fabsf(x), e = __expf(-2.f * a);
  float t = (1.f - e) / (1.f + e);
  return x < 0.f ? -t : t;
}

static const long SLOT_BI = 256L * 1024;  // one timestep of bi
static const long SLOT_DO = 256L * 512;   // one timestep of decout ring
static const long SLOT_XG = 256L * 2048;  // one timestep of xg

// ---------------------------------------------------------------------------
// bf16 MFMA GEMM: C[M,N] = act(A[M,K] @ W[N,K]^T + bias[N]); A split at ksplit
// across two sources (pred_in = [dec_x[:,:160] | dec_out]). 64x64 tile, 4 waves.
// ---------------------------------------------------------------------------
template <int ACT>
__global__ __launch_bounds__(256) void gemm_k(
    const u16* __restrict__ A1, long lda1, const u16* __restrict__ A2, long lda2, int ksplit,
    const u16* __restrict__ W, long ldw, const float* __restrict__ bias,
    u16* __restrict__ C, long ldc, int K) {
  const int lane = threadIdx.x & 63;
  const int wv = threadIdx.x >> 6;
  const int lr = lane & 15, lg = lane >> 4;
  const long mbase = (long)blockIdx.y * 64 + (wv >> 1) * 32;
  const long nbase = (long)blockIdx.x * 64 + (wv & 1) * 32;
  f32x4 acc[2][2] = {};
  for (int kk = 0; kk < K; kk += 32) {
    const int k0 = kk + lg * 8;
    bf16x8 a[2], b[2];
#pragma unroll
    for (int fm = 0; fm < 2; fm++) {
      const long row = mbase + fm * 16 + lr;
      const u16* p = (k0 < ksplit) ? (A1 + row * lda1 + k0)
                                   : (A2 + row * lda2 + (k0 - ksplit));
      a[fm] = *reinterpret_cast<const bf16x8*>(p);
    }
#pragma unroll
    for (int fn = 0; fn < 2; fn++) {
      const long col = nbase + fn * 16 + lr;
      b[fn] = *reinterpret_cast<const bf16x8*>(W + col * ldw + k0);
    }
#pragma unroll
    for (int fm = 0; fm < 2; fm++)
#pragma unroll
      for (int fn = 0; fn < 2; fn++)
        acc[fm][fn] = __builtin_amdgcn_mfma_f32_16x16x32_bf16(a[fm], b[fn], acc[fm][fn], 0, 0, 0);
  }
#pragma unroll
  for (int fm = 0; fm < 2; fm++)
#pragma unroll
    for (int fn = 0; fn < 2; fn++)
#pragma unroll
      for (int r = 0; r < 4; r++) {
        const long row = mbase + fm * 16 + lg * 4 + r;  // C/D: row=(lane>>4)*4+reg
        const long col = nbase + fn * 16 + lr;          //      col=lane&15
        float v = acc[fm][fn][r] + bias[col];
        if (ACT == 1) v = tnh(v);
        C[row * ldc + col] = f2bf(v);
      }
}

// ---------------------------------------------------------------------------
// Persistent chunk LSTM. MODE 0: biLSTM phase (2 dirs, history = bi, stride
// 1024). MODE 1: enc phase (ping-pong h0/h1). MODE 2: dec phase (ring histA,
// init h0, c continues). Block = 512 thr = 8 waves = 4 hcol-tiles x 2 khalves;
// covers 16 rows x 64 hcols. Group = 8 blocks (one row-tile, all 512 hcols).
// Weights in VGPRs (bf16x8 W[4][8] = 128 regs). c in regs across the chunk.
// ---------------------------------------------------------------------------
struct SeqP {
  const u16 *xgA, *xgB;
  const u16 *whA, *whB;
  float *cA, *cB;
  u16 *histA;        // MODE0: bi; MODE2: decout ring
  u16 *h0, *h1;      // MODE1: ping-pong; MODE2: h0 = initial h (h_enc0)
  u32 *cnt;          // per-group counters, stride 32 u32 (128B)
  int k, CH;
};

template <int MODE>
__global__ __launch_bounds__(512, 2) void lstm_seq_k(SeqP p) {
  const int tid = threadIdx.x;
  const int w = tid >> 6, lane = tid & 63, lr = lane & 15, lg = lane >> 4;
  const int hct = w & 3, kh = w >> 2;
  int dir, rt, kb;
  if (MODE == 0) { dir = blockIdx.x >> 7; rt = (blockIdx.x >> 3) & 15; kb = blockIdx.x & 7; }
  else           { dir = 0;               rt = blockIdx.x >> 3;        kb = blockIdx.x & 7; }
  const u16* xg = (MODE == 0 && dir) ? p.xgB : p.xgA;
  const u16* wh = (MODE == 0 && dir) ? p.whB : p.whA;
  float* cbuf   = (MODE == 0 && dir) ? p.cB  : p.cA;
  const int rbase = rt * 16;
  const int hc0 = kb * 64 + hct * 16;
  const int kofs = kh * 256;
  u32* cnt = p.cnt + (long)((MODE == 0) ? (dir * 16 + rt) : rt) * 32;

  // --- resident weights: 4 gates x 8 k-iters, bf16x8 each (128 VGPRs) ---
  bf16x8 W[4][8];
#pragma unroll
  for (int g = 0; g < 4; g++)
#pragma unroll
    for (int ki = 0; ki < 8; ki++)
      W[g][ki] = *reinterpret_cast<const bf16x8*>(
          wh + (long)(g * 512 + hc0 + lr) * 512 + kofs + ki * 32 + lg * 8);

  // --- resident cell state (kh0 waves use it) ---
  const bool zero_init = (MODE <= 1) && (p.k == 0);
  float creg[4];
#pragma unroll
  for (int r = 0; r < 4; r++) {
    creg[r] = 0.f;
    if (kh == 0 && !zero_init)
      creg[r] = cbuf[(long)(rbase + lg * 4 + r) * 512 + hc0 + lr];
  }

  __shared__ f32x4 lacc[4][64][4];  // [hct][lane][gate]  (16 KB)

  for (int ts = 0; ts < p.CH; ts++) {
    const int S = p.k * p.CH + ts;  // phase-global step index
    const u16* hp;
    u16* ho;
    long hstride;
    int slot;
    bool first;
    if (MODE == 0) {
      const int t = dir == 0 ? S : 255 - S;
      slot = dir == 0 ? ts : p.CH - 1 - ts;
      hstride = 1024;
      const int tp = dir == 0 ? t - 1 : t + 1;
      hp = p.histA + (long)tp * SLOT_BI + dir * 512;
      ho = p.histA + (long)t * SLOT_BI + dir * 512;
      first = (S == 0);
    } else if (MODE == 1) {
      slot = ts; hstride = 512;
      hp = (S & 1) ? p.h1 : p.h0;
      ho = (S & 1) ? p.h0 : p.h1;
      first = (S == 0);
    } else {
      slot = ts; hstride = 512;
      hp = (S == 0) ? p.h0 : p.histA + (long)((S - 1) & (p.CH - 1)) * SLOT_DO;
      ho = p.histA + (long)(S & (p.CH - 1)) * SLOT_DO;
      first = false;
    }

    f32x4 acc[4] = {};
    if (!first) {
#pragma unroll
      for (int ki = 0; ki < 8; ki++) {
        bf16x8 a = *reinterpret_cast<const bf16x8*>(
            hp + (long)(rbase + lr) * hstride + kofs + ki * 32 + lg * 8);
#pragma unroll
        for (int g = 0; g < 4; g++)
          acc[g] = __builtin_amdgcn_mfma_f32_16x16x32_bf16(a, W[g][ki], acc[g], 0, 0, 0);
      }
    }
    // combine K-halves through LDS
    if (kh == 1) {
#pragma unroll
      for (int g = 0; g < 4; g++) lacc[hct][lane][g] = acc[g];
    }
    __syncthreads();
    if (kh == 0) {
#pragma unroll
      for (int g = 0; g < 4; g++) acc[g] += lacc[hct][lane][g];
      const long xbase = (long)slot * SLOT_XG;
#pragma unroll
      for (int r = 0; r < 4; r++) {
        const long row = rbase + lg * 4 + r;
        const long xr = xbase + row * 2048;
        const int colh = hc0 + lr;
        float gi = acc[0][r] + bf2f(xg[xr + colh]);
        float gf = acc[1][r] + bf2f(xg[xr + 512 + colh]);
        float gg = acc[2][r] + bf2f(xg[xr + 1024 + colh]);
        float go = acc[3][r] + bf2f(xg[xr + 1536 + colh]);
        float cn = sigm(gf) * creg[r] + sigm(gi) * tnh(gg);
        creg[r] = cn;
        ho[row * hstride + colh] = f2bf(sigm(go) * tnh(cn));
      }
    }
    __syncthreads();  // h stores drained (vmcnt) before arrival
    if (tid == 0) {
      __threadfence();  // release: L2 writeback so other XCDs see our h
      __hip_atomic_fetch_add(cnt, 1u, __ATOMIC_RELAXED, __HIP_MEMORY_SCOPE_AGENT);
      if (ts != p.CH - 1) {
        const u32 tgt = 8u * (u32)(S + 1);
        while (__hip_atomic_load(cnt, __ATOMIC_RELAXED, __HIP_MEMORY_SCOPE_AGENT) < tgt)
          __builtin_amdgcn_s_sleep(2);
        __threadfence();  // acquire: invalidate so we see the group's h
      }
    }
    __syncthreads();
  }
  if (kh == 0) {
#pragma unroll
    for (int r = 0; r < 4; r++)
      cbuf[(long)(rbase + lg * 4 + r) * 512 + hc0 + lr] = creg[r];
  }
}

// ---------------------------------------------------------------------------
// Embedding gathers -> bf16, TIME-MAJOR output (row = t*256 + b).
// ---------------------------------------------------------------------------
__global__ __launch_bounds__(256) void embed_enc_k(
    const int* __restrict__ q, const int* __restrict__ a, const int* __restrict__ pos,
    const int* __restrict__ fmt, const float* __restrict__ tw, const float* __restrict__ aw,
    const float* __restrict__ pw, const float* __restrict__ fw, u16* __restrict__ out) {
  const long blk = blockIdx.x;  // t*256 + b
  const int t = (int)(blk >> 8), b = (int)(blk & 255);
  const long src = (long)b * 256 + t;  // inputs are [B][T]
  const int iq = q[src], ia = a[src], ip = pos[src], ifm = fmt[src];
  for (int col = threadIdx.x; col < 288; col += 256) {
    float v;
    if (col < 128)      v = tw[(long)iq * 128 + col];
    else if (col < 256) v = aw[(long)ia * 128 + (col - 128)];
    else if (col < 272) v = pw[(long)ip * 16 + (col - 256)];
    else                v = fw[(long)ifm * 16 + (col - 272)];
    out[blk * 288 + col] = f2bf(v);
  }
}

__global__ __launch_bounds__(256) void embed_dec_k(
    const int* __restrict__ q, const int* __restrict__ a, const int* __restrict__ pos,
    const int* __restrict__ fmt, const int* __restrict__ last_a,
    const float* __restrict__ tw, const float* __restrict__ aw,
    const float* __restrict__ pw, const float* __restrict__ fw, u16* __restrict__ out) {
  const long blk = blockIdx.x;  // t*256 + b
  const int t = (int)(blk >> 8), b = (int)(blk & 255);
  const long src = (long)b * 256 + t;
  const int iq = q[src], ip = pos[src], ifm = fmt[src];
  const int pa = (t == 0) ? last_a[b] : a[src - 1];  // teacher forcing shift
  for (int col = threadIdx.x; col < 288; col += 256) {
    float v;
    if (col < 128)      v = tw[(long)iq * 128 + col];
    else if (col < 144) v = pw[(long)ip * 16 + (col - 128)];
    else if (col < 160) v = fw[(long)ifm * 16 + (col - 144)];
    else                v = aw[(long)pa * 128 + (col - 160)];
    out[blk * 288 + col] = f2bf(v);
  }
}

// out[b*256 + t0 + tl] = sigmoid(hidden[row] . w2 + b2); row = tl*256 + b.
__global__ __launch_bounds__(256) void pred_out_k(
    const u16* __restrict__ hidden, const float* __restrict__ w2,
    const float* __restrict__ b2, float* __restrict__ out, int t0) {
  const long r = (long)blockIdx.x * 4 + (threadIdx.x >> 6);
  const int lane = threadIdx.x & 63;
  const u16* hp = hidden + r * 512 + lane * 8;
  const float* wp = w2 + lane * 8;
  float s = 0.f;
#pragma unroll
  for (int j = 0; j < 8; j++) s += bf2f(hp[j]) * wp[j];
  for (int off = 32; off > 0; off >>= 1) s += __shfl_down(s, off);
  if (lane == 0) out[(r & 255) * 256 + t0 + (r >> 8)] = sigm(s + b2[0]);
}

__global__ __launch_bounds__(256) void conv_bf16_k(const float* __restrict__ s,
                                                   u16* __restrict__ d, long n) {
  long i = (long)blockIdx.x * 256 + threadIdx.x;
  if (i < n) d[i] = f2bf(s[i]);
}
__global__ __launch_bounds__(256) void bias_sum_k(const float* __restrict__ a,
                                                  const float* __restrict__ b,
                                                  float* __restrict__ d, int n) {
  int i = blockIdx.x * 256 + threadIdx.x;
  if (i < n) d[i] = a[i] + b[i];
}
__global__ __launch_bounds__(256) void zero_k(u32* __restrict__ p, int n) {
  int i = blockIdx.x * 256 + threadIdx.x;
  if (i < n) p[i] = 0;
}

// ---------------------------------------------------------------------------
extern "C" void kernel_launch(void* const* d_in, const int* in_sizes, int n_in,
                              void* d_out, int out_size, void* d_ws, size_t ws_size,
                              hipStream_t stream) {
  const int* enc_q     = (const int*)d_in[0];
  const int* enc_a     = (const int*)d_in[1];
  const int* enc_pos   = (const int*)d_in[2];
  const int* enc_fmt   = (const int*)d_in[3];
  const int* dec_q     = (const int*)d_in[4];
  const int* dec_a     = (const int*)d_in[5];
  const int* dec_pos   = (const int*)d_in[6];
  const int* dec_fmt   = (const int*)d_in[7];
  const int* enc_last  = (const int*)d_in[8];
  const float* t_emb   = (const float*)d_in[9];
  const float* a_emb   = (const float*)d_in[10];
  const float* pos_emb = (const float*)d_in[11];
  const float* fmt_emb = (const float*)d_in[12];
  const float* bif_w_ih = (const float*)d_in[13];
  const float* bif_w_hh = (const float*)d_in[14];
  const float* bif_b_ih = (const float*)d_in[15];
  const float* bif_b_hh = (const float*)d_in[16];
  const float* bib_w_ih = (const float*)d_in[17];
  const float* bib_w_hh = (const float*)d_in[18];
  const float* bib_b_ih = (const float*)d_in[19];
  const float* bib_b_hh = (const float*)d_in[20];
  const float* enc_w_ih = (const float*)d_in[21];
  const float* enc_w_hh = (const float*)d_in[22];
  const float* enc_b_ih = (const float*)d_in[23];
  const float* enc_b_hh = (const float*)d_in[24];
  const float* dec_w_ih = (const float*)d_in[25];
  const float* dec_w_hh = (const float*)d_in[26];
  const float* dec_b_ih = (const float*)d_in[27];
  const float* dec_b_hh = (const float*)d_in[28];
  const float* pred_w1 = (const float*)d_in[29];
  const float* pred_b1 = (const float*)d_in[30];
  const float* pred_w2 = (const float*)d_in[31];
  const float* pred_b2 = (const float*)d_in[32];
  (void)in_sizes; (void)n_in; (void)out_size;

  char* base = (char*)d_ws;
  size_t off = 0;
  auto alloc = [&](size_t bytes) -> char* {
    char* p = base + off;
    off = (off + bytes + 255) & ~(size_t)255;
    return p;
  };

  // --- fixed region ---
  u16* wb_bif_ih = (u16*)alloc(2048L * 288 * 2);
  u16* wb_bib_ih = (u16*)alloc(2048L * 288 * 2);
  u16* wb_enc_ih = (u16*)alloc(2048L * 1024 * 2);
  u16* wb_dec_ih = (u16*)alloc(2048L * 288 * 2);
  u16* wb_bif_hh = (u16*)alloc(2048L * 512 * 2);
  u16* wb_bib_hh = (u16*)alloc(2048L * 512 * 2);
  u16* wb_enc_hh = (u16*)alloc(2048L * 512 * 2);
  u16* wb_dec_hh = (u16*)alloc(2048L * 512 * 2);
  u16* wb_pred1  = (u16*)alloc(512L * 672 * 2);
  float* bias_bif = (float*)alloc(2048 * 4);
  float* bias_bib = (float*)alloc(2048 * 4);
  float* bias_enc = (float*)alloc(2048 * 4);
  float* bias_dec = (float*)alloc(2048 * 4);
  float* c_bif = (float*)alloc(256L * 512 * 4);
  float* c_bib = (float*)alloc(256L * 512 * 4);
  float* c_enc = (float*)alloc(256L * 512 * 4);
  u16* h_enc0 = (u16*)alloc(256L * 512 * 2);
  u16* h_enc1 = (u16*)alloc(256L * 512 * 2);
  u32* cnt = (u32*)alloc(64L * 32 * 4);  // 64 group counters, 128B stride

  // --- big activations (time-major) ---
  u16* bi    = (u16*)alloc(65536L * 1024 * 2);
  u16* dec_x = (u16*)alloc(65536L * 288 * 2);
  u16* enc_x = (u16*)alloc(65536L * 288 * 2);  // dead after phase 1 -> reuse

  int CH = 32;
  while (CH > 4 && off + 2ull * CH * 256 * 2048 * 2 > ws_size) CH >>= 1;
  u16* X1 = (u16*)alloc((size_t)CH * 256 * 2048 * 2);
  u16* X2 = (u16*)alloc((size_t)CH * 256 * 2048 * 2);
  u16* decout = enc_x;                         // CH-slot ring [CH][256][512]
  u16* hidden = enc_x + (long)CH * 256 * 512;  // [CH*256][512]
  const int NCH = 256 / CH;

  zero_k<<<8, 256, 0, stream>>>(cnt, 64 * 32);  // counters must start at 0

  auto CV = [&](const float* s, u16* d, long n) {
    conv_bf16_k<<<dim3((unsigned)((n + 255) / 256)), dim3(256), 0, stream>>>(s, d, n);
  };
  CV(bif_w_ih, wb_bif_ih, 2048L * 288);
  CV(bib_w_ih, wb_bib_ih, 2048L * 288);
  CV(enc_w_ih, wb_enc_ih, 2048L * 1024);
  CV(dec_w_ih, wb_dec_ih, 2048L * 288);
  CV(bif_w_hh, wb_bif_hh, 2048L * 512);
  CV(bib_w_hh, wb_bib_hh, 2048L * 512);
  CV(enc_w_hh, wb_enc_hh, 2048L * 512);
  CV(dec_w_hh, wb_dec_hh, 2048L * 512);
  CV(pred_w1, wb_pred1, 512L * 672);
  bias_sum_k<<<8, 256, 0, stream>>>(bif_b_ih, bif_b_hh, bias_bif, 2048);
  bias_sum_k<<<8, 256, 0, stream>>>(bib_b_ih, bib_b_hh, bias_bib, 2048);
  bias_sum_k<<<8, 256, 0, stream>>>(enc_b_ih, enc_b_hh, bias_enc, 2048);
  bias_sum_k<<<8, 256, 0, stream>>>(dec_b_ih, dec_b_hh, bias_dec, 2048);

  embed_enc_k<<<65536, 256, 0, stream>>>(enc_q, enc_a, enc_pos, enc_fmt,
                                         t_emb, a_emb, pos_emb, fmt_emb, enc_x);
  embed_dec_k<<<65536, 256, 0, stream>>>(dec_q, dec_a, dec_pos, dec_fmt, enc_last,
                                         t_emb, a_emb, pos_emb, fmt_emb, dec_x);

  // ---- phase 1: bif (fwd) + bib (bwd) persistent chunks -> bi ----
  for (int k = 0; k < NCH; k++) {
    const int t0f = k * CH;
    const int t0b = 256 - (k + 1) * CH;
    gemm_k<0><<<dim3(32, CH * 4), 256, 0, stream>>>(
        enc_x + (long)t0f * 256 * 288, 288, enc_x, 288, 288,
        wb_bif_ih, 288, bias_bif, X1, 2048, 288);
    gemm_k<0><<<dim3(32, CH * 4), 256, 0, stream>>>(
        enc_x + (long)t0b * 256 * 288, 288, enc_x, 288, 288,
        wb_bib_ih, 288, bias_bib, X2, 2048, 288);
    SeqP sp{X1, X2, wb_bif_hh, wb_bib_hh, c_bif, c_bib,
            bi, nullptr, nullptr, cnt, k, CH};
    void* args[] = {&sp};
    hipLaunchCooperativeKernel(reinterpret_cast<void*>(&lstm_seq_k<0>),
                               dim3(256), dim3(512), args, 0, stream);
  }

  // ---- phase 2: enc LSTM persistent chunks (final state only) ----
  for (int k = 0; k < NCH; k++) {
    const int t0 = k * CH;
    gemm_k<0><<<dim3(32, CH * 4), 256, 0, stream>>>(
        bi + (long)t0 * SLOT_BI, 1024, bi, 1024, 1024,
        wb_enc_ih, 1024, bias_enc, X1, 2048, 1024);
    SeqP sp{X1, nullptr, wb_enc_hh, nullptr, c_enc, nullptr,
            nullptr, h_enc0, h_enc1, cnt + 32L * 32, k, CH};
    void* args[] = {&sp};
    hipLaunchCooperativeKernel(reinterpret_cast<void*>(&lstm_seq_k<1>),
                               dim3(128), dim3(512), args, 0, stream);
  }
  // final h in h_enc0 (t=255 odd -> ho = h0), final c in c_enc

  // ---- phase 3: dec LSTM persistent chunks + per-chunk head ----
  for (int k = 0; k < NCH; k++) {
    const int t0 = k * CH;
    gemm_k<0><<<dim3(32, CH * 4), 256, 0, stream>>>(
        dec_x + (long)t0 * 256 * 288, 288, dec_x, 288, 288,
        wb_dec_ih, 288, bias_dec, X1, 2048, 288);
    SeqP sp{X1, nullptr, wb_dec_hh, nullptr, c_enc, nullptr,
            decout, h_enc0, nullptr, cnt + 48L * 32, k, CH};
    void* args[] = {&sp};
    hipLaunchCooperativeKernel(reinterpret_cast<void*>(&lstm_seq_k<2>),
                               dim3(128), dim3(512), args, 0, stream);
    gemm_k<1><<<dim3(8, CH * 4), 256, 0, stream>>>(
        dec_x + (long)t0 * 256 * 288, 288, decout, 512, 160,
        wb_pred1, 672, pred_b1, hidden, 512, 672);
    pred_out_k<<<CH * 64, 256, 0, stream>>>(hidden, pred_w2, pred_b2, (float*)d_out, t0);
  }
}

// Round 4
// 10458.853 us; speedup vs baseline: 1.3930x; 1.3930x over previous
//
#include <hip/hip_runtime.h>

// ---------------------------------------------------------------------------
// SDKT model: embeddings -> biLSTM encoder -> enc LSTM -> dec LSTM -> MLP head
// B=256, T=256, H=512, G=2048, enc/dec input = 288, enc2 input = 1024.
// GEMMs bf16 MFMA (f32 accum). Recurrences: PERSISTENT cooperative chunk
// kernels, w_hh register-resident, c-state register-resident. Cross-block
// h exchange uses relaxed AGENT-scope atomic stores/loads (write-through /
// L2-bypass -> cross-XCD coherent per-access), so NO threadfence L2 flushes.
// Per-step scoped 8-block barrier via agent-scope atomic counter.
// Activations TIME-MAJOR [T][B][*].
// ---------------------------------------------------------------------------

using u16 = unsigned short;
using u32 = unsigned int;
using u64 = unsigned long long;
typedef float f32x4 __attribute__((ext_vector_type(4)));
typedef __bf16 bf16x8 __attribute__((ext_vector_type(8)));

__device__ __forceinline__ u16 f2bf(float f) {
  u32 u = __float_as_uint(f);
  u = (u + 0x7FFFu + ((u >> 16) & 1u)) >> 16;  // RNE
  return (u16)u;
}
__device__ __forceinline__ float bf2f(u16 h) { return __uint_as_float(((u32)h) << 16); }
__device__ __forceinline__ float sigm(float x) { return 1.f / (1.f + __expf(-x)); }
__device__ __forceinline__ float tnh(float x) {
  float a = fabsf(x), e = __expf(-2.f * a);
  float t = (1.f - e) / (1.f + e);
  return x < 0.f ? -t : t;
}

// agent-coherent primitives for cross-XCD h exchange (no fences needed)
__device__ __forceinline__ u64 ldA_u64(const u16* p) {
  return __hip_atomic_load((const u64*)p, __ATOMIC_RELAXED, __HIP_MEMORY_SCOPE_AGENT);
}
__device__ __forceinline__ void stA_u16(u16* p, u16 v) {
  __hip_atomic_store(p, v, __ATOMIC_RELAXED, __HIP_MEMORY_SCOPE_AGENT);
}

static const long SLOT_BI = 256L * 1024;  // one timestep of bi
static const long SLOT_DO = 256L * 512;   // one timestep of decout ring
static const long SLOT_XG = 256L * 2048;  // one timestep of xg

// ---------------------------------------------------------------------------
// bf16 MFMA GEMM: C[M,N] = act(A[M,K] @ W[N,K]^T + bias[N]); A split at ksplit
// across two sources (pred_in = [dec_x[:,:160] | dec_out]). 64x64 tile, 4 waves.
// ---------------------------------------------------------------------------
template <int ACT>
__global__ __launch_bounds__(256) void gemm_k(
    const u16* __restrict__ A1, long lda1, const u16* __restrict__ A2, long lda2, int ksplit,
    const u16* __restrict__ W, long ldw, const float* __restrict__ bias,
    u16* __restrict__ C, long ldc, int K) {
  const int lane = threadIdx.x & 63;
  const int wv = threadIdx.x >> 6;
  const int lr = lane & 15, lg = lane >> 4;
  const long mbase = (long)blockIdx.y * 64 + (wv >> 1) * 32;
  const long nbase = (long)blockIdx.x * 64 + (wv & 1) * 32;
  f32x4 acc[2][2] = {};
  for (int kk = 0; kk < K; kk += 32) {
    const int k0 = kk + lg * 8;
    bf16x8 a[2], b[2];
#pragma unroll
    for (int fm = 0; fm < 2; fm++) {
      const long row = mbase + fm * 16 + lr;
      const u16* p = (k0 < ksplit) ? (A1 + row * lda1 + k0)
                                   : (A2 + row * lda2 + (k0 - ksplit));
      a[fm] = *reinterpret_cast<const bf16x8*>(p);
    }
#pragma unroll
    for (int fn = 0; fn < 2; fn++) {
      const long col = nbase + fn * 16 + lr;
      b[fn] = *reinterpret_cast<const bf16x8*>(W + col * ldw + k0);
    }
#pragma unroll
    for (int fm = 0; fm < 2; fm++)
#pragma unroll
      for (int fn = 0; fn < 2; fn++)
        acc[fm][fn] = __builtin_amdgcn_mfma_f32_16x16x32_bf16(a[fm], b[fn], acc[fm][fn], 0, 0, 0);
  }
#pragma unroll
  for (int fm = 0; fm < 2; fm++)
#pragma unroll
    for (int fn = 0; fn < 2; fn++)
#pragma unroll
      for (int r = 0; r < 4; r++) {
        const long row = mbase + fm * 16 + lg * 4 + r;  // C/D: row=(lane>>4)*4+reg
        const long col = nbase + fn * 16 + lr;          //      col=lane&15
        float v = acc[fm][fn][r] + bias[col];
        if (ACT == 1) v = tnh(v);
        C[row * ldc + col] = f2bf(v);
      }
}

// ---------------------------------------------------------------------------
// Persistent chunk LSTM. MODE 0: biLSTM (2 dirs, history = bi, stride 1024).
// MODE 1: enc (ping-pong h0/h1). MODE 2: dec (ring histA, init h0, c cont.).
// Block = 512 thr = 8 waves = 4 hcol-tiles x 2 khalves; 16 rows x 64 hcols.
// Group = 8 blocks (one row-tile, all 512 hcols). W in regs, c in regs.
// ---------------------------------------------------------------------------
struct SeqP {
  const u16 *xgA, *xgB;
  const u16 *whA, *whB;
  float *cA, *cB;
  u16 *histA;        // MODE0: bi; MODE2: decout ring
  u16 *h0, *h1;      // MODE1: ping-pong; MODE2: h0 = initial h (h_enc0)
  u32 *cnt;          // per-group counters, stride 32 u32 (128B)
  int k, CH;
};

template <int MODE>
__global__ __launch_bounds__(512, 2) void lstm_seq_k(SeqP p) {
  const int tid = threadIdx.x;
  const int w = tid >> 6, lane = tid & 63, lr = lane & 15, lg = lane >> 4;
  const int hct = w & 3, kh = w >> 2;
  int dir, rt, kb;
  if (MODE == 0) { dir = blockIdx.x >> 7; rt = (blockIdx.x >> 3) & 15; kb = blockIdx.x & 7; }
  else           { dir = 0;               rt = blockIdx.x >> 3;        kb = blockIdx.x & 7; }
  const u16* xg = (MODE == 0 && dir) ? p.xgB : p.xgA;
  const u16* wh = (MODE == 0 && dir) ? p.whB : p.whA;
  float* cbuf   = (MODE == 0 && dir) ? p.cB  : p.cA;
  const int rbase = rt * 16;
  const int hc0 = kb * 64 + hct * 16;
  const int kofs = kh * 256;
  u32* cnt = p.cnt + (long)((MODE == 0) ? (dir * 16 + rt) : rt) * 32;

  // --- resident weights: 4 gates x 8 k-iters, bf16x8 each ---
  bf16x8 W[4][8];
#pragma unroll
  for (int g = 0; g < 4; g++)
#pragma unroll
    for (int ki = 0; ki < 8; ki++)
      W[g][ki] = *reinterpret_cast<const bf16x8*>(
          wh + (long)(g * 512 + hc0 + lr) * 512 + kofs + ki * 32 + lg * 8);

  // --- resident cell state (kh0 waves use it) ---
  const bool zero_init = (MODE <= 1) && (p.k == 0);
  float creg[4];
#pragma unroll
  for (int r = 0; r < 4; r++) {
    creg[r] = 0.f;
    if (kh == 0 && !zero_init)
      creg[r] = cbuf[(long)(rbase + lg * 4 + r) * 512 + hc0 + lr];
  }

  __shared__ f32x4 lacc[4][64][4];  // [hct][lane][gate]  (16 KB)

  for (int ts = 0; ts < p.CH; ts++) {
    const int S = p.k * p.CH + ts;  // phase-global step index
    const u16* hp;
    u16* ho;
    long hstride;
    int slot;
    bool first;
    if (MODE == 0) {
      const int t = dir == 0 ? S : 255 - S;
      slot = dir == 0 ? ts : p.CH - 1 - ts;
      hstride = 1024;
      const int tp = dir == 0 ? t - 1 : t + 1;
      hp = p.histA + (long)tp * SLOT_BI + dir * 512;
      ho = p.histA + (long)t * SLOT_BI + dir * 512;
      first = (S == 0);
    } else if (MODE == 1) {
      slot = ts; hstride = 512;
      hp = (S & 1) ? p.h1 : p.h0;
      ho = (S & 1) ? p.h0 : p.h1;
      first = (S == 0);
    } else {
      slot = ts; hstride = 512;
      hp = (S == 0) ? p.h0 : p.histA + (long)((S - 1) & (p.CH - 1)) * SLOT_DO;
      ho = p.histA + (long)(S & (p.CH - 1)) * SLOT_DO;
      first = false;
    }

    f32x4 acc[4] = {};
    if (!first) {
      // issue ALL h loads (agent-coherent, L2-bypass) before any use -> pipelined
      union AU { u64 q[2]; bf16x8 v; } au[8];
      const u16* abase = hp + (long)(rbase + lr) * hstride + kofs;
#pragma unroll
      for (int ki = 0; ki < 8; ki++) {
        au[ki].q[0] = ldA_u64(abase + ki * 32 + lg * 8);
        au[ki].q[1] = ldA_u64(abase + ki * 32 + lg * 8 + 4);
      }
#pragma unroll
      for (int ki = 0; ki < 8; ki++) {
#pragma unroll
        for (int g = 0; g < 4; g++)
          acc[g] = __builtin_amdgcn_mfma_f32_16x16x32_bf16(au[ki].v, W[g][ki], acc[g], 0, 0, 0);
      }
    }
    // combine K-halves through LDS
    if (kh == 1) {
#pragma unroll
      for (int g = 0; g < 4; g++) lacc[hct][lane][g] = acc[g];
    }
    __syncthreads();
    if (kh == 0) {
#pragma unroll
      for (int g = 0; g < 4; g++) acc[g] += lacc[hct][lane][g];
      const long xbase = (long)slot * SLOT_XG;
#pragma unroll
      for (int r = 0; r < 4; r++) {
        const long row = rbase + lg * 4 + r;
        const long xr = xbase + row * 2048;
        const int colh = hc0 + lr;
        float gi = acc[0][r] + bf2f(xg[xr + colh]);
        float gf = acc[1][r] + bf2f(xg[xr + 512 + colh]);
        float gg = acc[2][r] + bf2f(xg[xr + 1024 + colh]);
        float go = acc[3][r] + bf2f(xg[xr + 1536 + colh]);
        float cn = sigm(gf) * creg[r] + sigm(gi) * tnh(gg);
        creg[r] = cn;
        stA_u16(&ho[row * hstride + colh], f2bf(sigm(go) * tnh(cn)));
      }
    }
    __syncthreads();  // vmcnt(0) drained: all h stores complete at coherence pt
    if (tid == 0) {
      __hip_atomic_fetch_add(cnt, 1u, __ATOMIC_RELAXED, __HIP_MEMORY_SCOPE_AGENT);
      if (ts != p.CH - 1) {
        const u32 tgt = 8u * (u32)(S + 1);
        while (__hip_atomic_load(cnt, __ATOMIC_RELAXED, __HIP_MEMORY_SCOPE_AGENT) < tgt)
          __builtin_amdgcn_s_sleep(1);
      }
    }
    __syncthreads();
  }
  if (kh == 0) {
#pragma unroll
    for (int r = 0; r < 4; r++)
      cbuf[(long)(rbase + lg * 4 + r) * 512 + hc0 + lr] = creg[r];
  }
}

// ---------------------------------------------------------------------------
// Embedding gathers -> bf16, TIME-MAJOR output (row = t*256 + b).
// ---------------------------------------------------------------------------
__global__ __launch_bounds__(256) void embed_enc_k(
    const int* __restrict__ q, const int* __restrict__ a, const int* __restrict__ pos,
    const int* __restrict__ fmt, const float* __restrict__ tw, const float* __restrict__ aw,
    const float* __restrict__ pw, const float* __restrict__ fw, u16* __restrict__ out) {
  const long blk = blockIdx.x;  // t*256 + b
  const int t = (int)(blk >> 8), b = (int)(blk & 255);
  const long src = (long)b * 256 + t;  // inputs are [B][T]
  const int iq = q[src], ia = a[src], ip = pos[src], ifm = fmt[src];
  for (int col = threadIdx.x; col < 288; col += 256) {
    float v;
    if (col < 128)      v = tw[(long)iq * 128 + col];
    else if (col < 256) v = aw[(long)ia * 128 + (col - 128)];
    else if (col < 272) v = pw[(long)ip * 16 + (col - 256)];
    else                v = fw[(long)ifm * 16 + (col - 272)];
    out[blk * 288 + col] = f2bf(v);
  }
}

__global__ __launch_bounds__(256) void embed_dec_k(
    const int* __restrict__ q, const int* __restrict__ a, const int* __restrict__ pos,
    const int* __restrict__ fmt, const int* __restrict__ last_a,
    const float* __restrict__ tw, const float* __restrict__ aw,
    const float* __restrict__ pw, const float* __restrict__ fw, u16* __restrict__ out) {
  const long blk = blockIdx.x;  // t*256 + b
  const int t = (int)(blk >> 8), b = (int)(blk & 255);
  const long src = (long)b * 256 + t;
  const int iq = q[src], ip = pos[src], ifm = fmt[src];
  const int pa = (t == 0) ? last_a[b] : a[src - 1];  // teacher forcing shift
  for (int col = threadIdx.x; col < 288; col += 256) {
    float v;
    if (col < 128)      v = tw[(long)iq * 128 + col];
    else if (col < 144) v = pw[(long)ip * 16 + (col - 128)];
    else if (col < 160) v = fw[(long)ifm * 16 + (col - 144)];
    else                v = aw[(long)pa * 128 + (col - 160)];
    out[blk * 288 + col] = f2bf(v);
  }
}

// out[b*256 + t0 + tl] = sigmoid(hidden[row] . w2 + b2); row = tl*256 + b.
__global__ __launch_bounds__(256) void pred_out_k(
    const u16* __restrict__ hidden, const float* __restrict__ w2,
    const float* __restrict__ b2, float* __restrict__ out, int t0) {
  const long r = (long)blockIdx.x * 4 + (threadIdx.x >> 6);
  const int lane = threadIdx.x & 63;
  const u16* hp = hidden + r * 512 + lane * 8;
  const float* wp = w2 + lane * 8;
  float s = 0.f;
#pragma unroll
  for (int j = 0; j < 8; j++) s += bf2f(hp[j]) * wp[j];
  for (int off = 32; off > 0; off >>= 1) s += __shfl_down(s, off);
  if (lane == 0) out[(r & 255) * 256 + t0 + (r >> 8)] = sigm(s + b2[0]);
}

__global__ __launch_bounds__(256) void conv_bf16_k(const float* __restrict__ s,
                                                   u16* __restrict__ d, long n) {
  long i = (long)blockIdx.x * 256 + threadIdx.x;
  if (i < n) d[i] = f2bf(s[i]);
}
__global__ __launch_bounds__(256) void bias_sum_k(const float* __restrict__ a,
                                                  const float* __restrict__ b,
                                                  float* __restrict__ d, int n) {
  int i = blockIdx.x * 256 + threadIdx.x;
  if (i < n) d[i] = a[i] + b[i];
}
__global__ __launch_bounds__(256) void zero_k(u32* __restrict__ p, int n) {
  int i = blockIdx.x * 256 + threadIdx.x;
  if (i < n) p[i] = 0;
}

// ---------------------------------------------------------------------------
extern "C" void kernel_launch(void* const* d_in, const int* in_sizes, int n_in,
                              void* d_out, int out_size, void* d_ws, size_t ws_size,
                              hipStream_t stream) {
  const int* enc_q     = (const int*)d_in[0];
  const int* enc_a     = (const int*)d_in[1];
  const int* enc_pos   = (const int*)d_in[2];
  const int* enc_fmt   = (const int*)d_in[3];
  const int* dec_q     = (const int*)d_in[4];
  const int* dec_a     = (const int*)d_in[5];
  const int* dec_pos   = (const int*)d_in[6];
  const int* dec_fmt   = (const int*)d_in[7];
  const int* enc_last  = (const int*)d_in[8];
  const float* t_emb   = (const float*)d_in[9];
  const float* a_emb   = (const float*)d_in[10];
  const float* pos_emb = (const float*)d_in[11];
  const float* fmt_emb = (const float*)d_in[12];
  const float* bif_w_ih = (const float*)d_in[13];
  const float* bif_w_hh = (const float*)d_in[14];
  const float* bif_b_ih = (const float*)d_in[15];
  const float* bif_b_hh = (const float*)d_in[16];
  const float* bib_w_ih = (const float*)d_in[17];
  const float* bib_w_hh = (const float*)d_in[18];
  const float* bib_b_ih = (const float*)d_in[19];
  const float* bib_b_hh = (const float*)d_in[20];
  const float* enc_w_ih = (const float*)d_in[21];
  const float* enc_w_hh = (const float*)d_in[22];
  const float* enc_b_ih = (const float*)d_in[23];
  const float* enc_b_hh = (const float*)d_in[24];
  const float* dec_w_ih = (const float*)d_in[25];
  const float* dec_w_hh = (const float*)d_in[26];
  const float* dec_b_ih = (const float*)d_in[27];
  const float* dec_b_hh = (const float*)d_in[28];
  const float* pred_w1 = (const float*)d_in[29];
  const float* pred_b1 = (const float*)d_in[30];
  const float* pred_w2 = (const float*)d_in[31];
  const float* pred_b2 = (const float*)d_in[32];
  (void)in_sizes; (void)n_in; (void)out_size;

  char* base = (char*)d_ws;
  size_t off = 0;
  auto alloc = [&](size_t bytes) -> char* {
    char* p = base + off;
    off = (off + bytes + 255) & ~(size_t)255;
    return p;
  };

  // --- fixed region ---
  u16* wb_bif_ih = (u16*)alloc(2048L * 288 * 2);
  u16* wb_bib_ih = (u16*)alloc(2048L * 288 * 2);
  u16* wb_enc_ih = (u16*)alloc(2048L * 1024 * 2);
  u16* wb_dec_ih = (u16*)alloc(2048L * 288 * 2);
  u16* wb_bif_hh = (u16*)alloc(2048L * 512 * 2);
  u16* wb_bib_hh = (u16*)alloc(2048L * 512 * 2);
  u16* wb_enc_hh = (u16*)alloc(2048L * 512 * 2);
  u16* wb_dec_hh = (u16*)alloc(2048L * 512 * 2);
  u16* wb_pred1  = (u16*)alloc(512L * 672 * 2);
  float* bias_bif = (float*)alloc(2048 * 4);
  float* bias_bib = (float*)alloc(2048 * 4);
  float* bias_enc = (float*)alloc(2048 * 4);
  float* bias_dec = (float*)alloc(2048 * 4);
  float* c_bif = (float*)alloc(256L * 512 * 4);
  float* c_bib = (float*)alloc(256L * 512 * 4);
  float* c_enc = (float*)alloc(256L * 512 * 4);
  u16* h_enc0 = (u16*)alloc(256L * 512 * 2);
  u16* h_enc1 = (u16*)alloc(256L * 512 * 2);
  u32* cnt = (u32*)alloc(64L * 32 * 4);  // 64 group counters, 128B stride

  // --- big activations (time-major) ---
  u16* bi    = (u16*)alloc(65536L * 1024 * 2);
  u16* dec_x = (u16*)alloc(65536L * 288 * 2);
  u16* enc_x = (u16*)alloc(65536L * 288 * 2);  // dead after phase 1 -> reuse

  int CH = 64;
  while (CH > 4 && off + 2ull * CH * 256 * 2048 * 2 > ws_size) CH >>= 1;
  // decout+hidden overlay enc_x: need 2*CH*256*512*2 <= 65536*288*2 -> CH<=64 ok
  u16* X1 = (u16*)alloc((size_t)CH * 256 * 2048 * 2);
  u16* X2 = (u16*)alloc((size_t)CH * 256 * 2048 * 2);
  u16* decout = enc_x;                         // CH-slot ring [CH][256][512]
  u16* hidden = enc_x + (long)CH * 256 * 512;  // [CH*256][512]
  const int NCH = 256 / CH;

  zero_k<<<8, 256, 0, stream>>>(cnt, 64 * 32);  // counters must start at 0

  auto CV = [&](const float* s, u16* d, long n) {
    conv_bf16_k<<<dim3((unsigned)((n + 255) / 256)), dim3(256), 0, stream>>>(s, d, n);
  };
  CV(bif_w_ih, wb_bif_ih, 2048L * 288);
  CV(bib_w_ih, wb_bib_ih, 2048L * 288);
  CV(enc_w_ih, wb_enc_ih, 2048L * 1024);
  CV(dec_w_ih, wb_dec_ih, 2048L * 288);
  CV(bif_w_hh, wb_bif_hh, 2048L * 512);
  CV(bib_w_hh, wb_bib_hh, 2048L * 512);
  CV(enc_w_hh, wb_enc_hh, 2048L * 512);
  CV(dec_w_hh, wb_dec_hh, 2048L * 512);
  CV(pred_w1, wb_pred1, 512L * 672);
  bias_sum_k<<<8, 256, 0, stream>>>(bif_b_ih, bif_b_hh, bias_bif, 2048);
  bias_sum_k<<<8, 256, 0, stream>>>(bib_b_ih, bib_b_hh, bias_bib, 2048);
  bias_sum_k<<<8, 256, 0, stream>>>(enc_b_ih, enc_b_hh, bias_enc, 2048);
  bias_sum_k<<<8, 256, 0, stream>>>(dec_b_ih, dec_b_hh, bias_dec, 2048);

  embed_enc_k<<<65536, 256, 0, stream>>>(enc_q, enc_a, enc_pos, enc_fmt,
                                         t_emb, a_emb, pos_emb, fmt_emb, enc_x);
  embed_dec_k<<<65536, 256, 0, stream>>>(dec_q, dec_a, dec_pos, dec_fmt, enc_last,
                                         t_emb, a_emb, pos_emb, fmt_emb, dec_x);

  // ---- phase 1: bif (fwd) + bib (bwd) persistent chunks -> bi ----
  for (int k = 0; k < NCH; k++) {
    const int t0f = k * CH;
    const int t0b = 256 - (k + 1) * CH;
    gemm_k<0><<<dim3(32, CH * 4), 256, 0, stream>>>(
        enc_x + (long)t0f * 256 * 288, 288, enc_x, 288, 288,
        wb_bif_ih, 288, bias_bif, X1, 2048, 288);
    gemm_k<0><<<dim3(32, CH * 4), 256, 0, stream>>>(
        enc_x + (long)t0b * 256 * 288, 288, enc_x, 288, 288,
        wb_bib_ih, 288, bias_bib, X2, 2048, 288);
    SeqP sp{X1, X2, wb_bif_hh, wb_bib_hh, c_bif, c_bib,
            bi, nullptr, nullptr, cnt, k, CH};
    void* args[] = {&sp};
    hipLaunchCooperativeKernel(reinterpret_cast<void*>(&lstm_seq_k<0>),
                               dim3(256), dim3(512), args, 0, stream);
  }

  // ---- phase 2: enc LSTM persistent chunks (final state only) ----
  for (int k = 0; k < NCH; k++) {
    const int t0 = k * CH;
    gemm_k<0><<<dim3(32, CH * 4), 256, 0, stream>>>(
        bi + (long)t0 * SLOT_BI, 1024, bi, 1024, 1024,
        wb_enc_ih, 1024, bias_enc, X1, 2048, 1024);
    SeqP sp{X1, nullptr, wb_enc_hh, nullptr, c_enc, nullptr,
            nullptr, h_enc0, h_enc1, cnt + 32L * 32, k, CH};
    void* args[] = {&sp};
    hipLaunchCooperativeKernel(reinterpret_cast<void*>(&lstm_seq_k<1>),
                               dim3(128), dim3(512), args, 0, stream);
  }
  // final h in h_enc0 (t=255 odd -> ho = h0), final c in c_enc

  // ---- phase 3: dec LSTM persistent chunks + per-chunk head ----
  for (int k = 0; k < NCH; k++) {
    const int t0 = k * CH;
    gemm_k<0><<<dim3(32, CH * 4), 256, 0, stream>>>(
        dec_x + (long)t0 * 256 * 288, 288, dec_x, 288, 288,
        wb_dec_ih, 288, bias_dec, X1, 2048, 288);
    SeqP sp{X1, nullptr, wb_dec_hh, nullptr, c_enc, nullptr,
            decout, h_enc0, nullptr, cnt + 48L * 32, k, CH};
    void* args[] = {&sp};
    hipLaunchCooperativeKernel(reinterpret_cast<void*>(&lstm_seq_k<2>),
                               dim3(128), dim3(512), args, 0, stream);
    gemm_k<1><<<dim3(8, CH * 4), 256, 0, stream>>>(
        dec_x + (long)t0 * 256 * 288, 288, decout, 512, 160,
        wb_pred1, 672, pred_b1, hidden, 512, 672);
    pred_out_k<<<CH * 64, 256, 0, stream>>>(hidden, pred_w2, pred_b2, (float*)d_out, t0);
  }
}

// Round 7
// 9515.603 us; speedup vs baseline: 1.5311x; 1.0991x over previous
//
#include <hip/hip_runtime.h>

// ---------------------------------------------------------------------------
// SDKT model: embeddings -> biLSTM encoder -> enc LSTM -> dec LSTM -> MLP head
// B=256, T=256, H=512, G=2048, enc/dec input = 288, enc2 input = 1024.
// GEMMs bf16 MFMA (f32 accum). Recurrences: PERSISTENT chunk kernels launched
// as REGULAR dispatches (grid <= 256 blocks = #CUs, >=1 block/CU occupancy =>
// all blocks resident; r4-proven spin design). w_hh register-resident,
// c-state register-resident per chunk. Cross-block h exchange via relaxed
// AGENT-scope atomics (L2-bypass, cross-XCD coherent; fence-free).
// Per-step scoped 8-block barrier via agent-scope atomic counter.
// Activations TIME-MAJOR [T][B][*].
// ---------------------------------------------------------------------------

using u16 = unsigned short;
using u32 = unsigned int;
using u64 = unsigned long long;
typedef float f32x4 __attribute__((ext_vector_type(4)));
typedef __bf16 bf16x8 __attribute__((ext_vector_type(8)));

__device__ __forceinline__ u16 f2bf(float f) {
  u32 u = __float_as_uint(f);
  u = (u + 0x7FFFu + ((u >> 16) & 1u)) >> 16;  // RNE
  return (u16)u;
}
__device__ __forceinline__ float bf2f(u16 h) { return __uint_as_float(((u32)h) << 16); }
__device__ __forceinline__ float sigm(float x) { return 1.f / (1.f + __expf(-x)); }
__device__ __forceinline__ float tnh(float x) {
  float a = fabsf(x), e = __expf(-2.f * a);
  float t = (1.f - e) / (1.f + e);
  return x < 0.f ? -t : t;
}

// agent-coherent primitives for cross-XCD h exchange (no fences needed)
__device__ __forceinline__ u64 ldA_u64(const u16* p) {
  return __hip_atomic_load((const u64*)p, __ATOMIC_RELAXED, __HIP_MEMORY_SCOPE_AGENT);
}
__device__ __forceinline__ void stA_u16(u16* p, u16 v) {
  __hip_atomic_store(p, v, __ATOMIC_RELAXED, __HIP_MEMORY_SCOPE_AGENT);
}

static const long SLOT_BI = 256L * 1024;  // one timestep of bi
static const long SLOT_DO = 256L * 512;   // one timestep of decout ring
static const long SLOT_XG = 256L * 2048;  // one timestep of xg

// ---------------------------------------------------------------------------
// bf16 MFMA GEMM: C[M,N] = act(A[M,K] @ W[N,K]^T + bias[N]); A split at ksplit
// across two sources (pred_in = [dec_x[:,:160] | dec_out]). 64x64 tile, 4 waves.
// ---------------------------------------------------------------------------
template <int ACT>
__global__ __launch_bounds__(256) void gemm_k(
    const u16* __restrict__ A1, long lda1, const u16* __restrict__ A2, long lda2, int ksplit,
    const u16* __restrict__ W, long ldw, const float* __restrict__ bias,
    u16* __restrict__ C, long ldc, int K) {
  const int lane = threadIdx.x & 63;
  const int wv = threadIdx.x >> 6;
  const int lr = lane & 15, lg = lane >> 4;
  const long mbase = (long)blockIdx.y * 64 + (wv >> 1) * 32;
  const long nbase = (long)blockIdx.x * 64 + (wv & 1) * 32;
  f32x4 acc[2][2] = {};
  for (int kk = 0; kk < K; kk += 32) {
    const int k0 = kk + lg * 8;
    bf16x8 a[2], b[2];
#pragma unroll
    for (int fm = 0; fm < 2; fm++) {
      const long row = mbase + fm * 16 + lr;
      const u16* p = (k0 < ksplit) ? (A1 + row * lda1 + k0)
                                   : (A2 + row * lda2 + (k0 - ksplit));
      a[fm] = *reinterpret_cast<const bf16x8*>(p);
    }
#pragma unroll
    for (int fn = 0; fn < 2; fn++) {
      const long col = nbase + fn * 16 + lr;
      b[fn] = *reinterpret_cast<const bf16x8*>(W + col * ldw + k0);
    }
#pragma unroll
    for (int fm = 0; fm < 2; fm++)
#pragma unroll
      for (int fn = 0; fn < 2; fn++)
        acc[fm][fn] = __builtin_amdgcn_mfma_f32_16x16x32_bf16(a[fm], b[fn], acc[fm][fn], 0, 0, 0);
  }
#pragma unroll
  for (int fm = 0; fm < 2; fm++)
#pragma unroll
    for (int fn = 0; fn < 2; fn++)
#pragma unroll
      for (int r = 0; r < 4; r++) {
        const long row = mbase + fm * 16 + lg * 4 + r;  // C/D: row=(lane>>4)*4+reg
        const long col = nbase + fn * 16 + lr;          //      col=lane&15
        float v = acc[fm][fn][r] + bias[col];
        if (ACT == 1) v = tnh(v);
        C[row * ldc + col] = f2bf(v);
      }
}

// ---------------------------------------------------------------------------
// Persistent chunk LSTM (r4-proven). MODE 0: biLSTM (2 dirs, history = bi,
// stride 1024). MODE 1: enc (ping-pong h0/h1). MODE 2: dec (ring histA, init
// h0, c continues). Block = 512 thr = 8 waves = 4 hcol-tiles x 2 khalves;
// 16 rows x 64 hcols. Group = 8 blocks. W in regs, c in regs per chunk.
// ---------------------------------------------------------------------------
struct SeqP {
  const u16 *xgA, *xgB;
  const u16 *whA, *whB;
  float *cA, *cB;
  u16 *histA;        // MODE0: bi; MODE2: decout ring
  u16 *h0, *h1;      // MODE1: ping-pong; MODE2: h0 = initial h (h_enc0)
  u32 *cnt;          // per-group counters, stride 32 u32 (128B)
  int k, CH;
};

template <int MODE>
__global__ __launch_bounds__(512, 2) void lstm_seq_k(SeqP p) {
  const int tid = threadIdx.x;
  const int w = tid >> 6, lane = tid & 63, lr = lane & 15, lg = lane >> 4;
  const int hct = w & 3, kh = w >> 2;
  int dir, rt, kb;
  if (MODE == 0) { dir = blockIdx.x >> 7; rt = (blockIdx.x >> 3) & 15; kb = blockIdx.x & 7; }
  else           { dir = 0;               rt = blockIdx.x >> 3;        kb = blockIdx.x & 7; }
  const u16* xg = (MODE == 0 && dir) ? p.xgB : p.xgA;
  const u16* wh = (MODE == 0 && dir) ? p.whB : p.whA;
  float* cbuf   = (MODE == 0 && dir) ? p.cB  : p.cA;
  const int rbase = rt * 16;
  const int hc0 = kb * 64 + hct * 16;
  const int kofs = kh * 256;
  u32* cnt = p.cnt + (long)((MODE == 0) ? (dir * 16 + rt) : rt) * 32;

  // --- resident weights: 4 gates x 8 k-iters, bf16x8 each ---
  bf16x8 W[4][8];
#pragma unroll
  for (int g = 0; g < 4; g++)
#pragma unroll
    for (int ki = 0; ki < 8; ki++)
      W[g][ki] = *reinterpret_cast<const bf16x8*>(
          wh + (long)(g * 512 + hc0 + lr) * 512 + kofs + ki * 32 + lg * 8);

  // --- resident cell state (kh0 waves use it) ---
  const bool zero_init = (MODE <= 1) && (p.k == 0);
  float creg[4];
#pragma unroll
  for (int r = 0; r < 4; r++) {
    creg[r] = 0.f;
    if (kh == 0 && !zero_init)
      creg[r] = cbuf[(long)(rbase + lg * 4 + r) * 512 + hc0 + lr];
  }

  __shared__ f32x4 lacc[4][64][4];  // [hct][lane][gate]  (16 KB)

  for (int ts = 0; ts < p.CH; ts++) {
    const int S = p.k * p.CH + ts;  // phase-global step index
    const u16* hp;
    u16* ho;
    long hstride;
    int slot;
    bool first;
    if (MODE == 0) {
      const int t = dir == 0 ? S : 255 - S;
      slot = dir == 0 ? ts : p.CH - 1 - ts;
      hstride = 1024;
      const int tp = dir == 0 ? t - 1 : t + 1;
      hp = p.histA + (long)tp * SLOT_BI + dir * 512;
      ho = p.histA + (long)t * SLOT_BI + dir * 512;
      first = (S == 0);
    } else if (MODE == 1) {
      slot = ts; hstride = 512;
      hp = (S & 1) ? p.h1 : p.h0;
      ho = (S & 1) ? p.h0 : p.h1;
      first = (S == 0);
    } else {
      slot = ts; hstride = 512;
      hp = (S == 0) ? p.h0 : p.histA + (long)((S - 1) & (p.CH - 1)) * SLOT_DO;
      ho = p.histA + (long)(S & (p.CH - 1)) * SLOT_DO;
      first = false;
    }

    f32x4 acc[4] = {};
    if (!first) {
      // issue ALL h loads (agent-coherent, L2-bypass) before any use -> pipelined
      union AU { u64 q[2]; bf16x8 v; } au[8];
      const u16* abase = hp + (long)(rbase + lr) * hstride + kofs;
#pragma unroll
      for (int ki = 0; ki < 8; ki++) {
        au[ki].q[0] = ldA_u64(abase + ki * 32 + lg * 8);
        au[ki].q[1] = ldA_u64(abase + ki * 32 + lg * 8 + 4);
      }
#pragma unroll
      for (int ki = 0; ki < 8; ki++) {
#pragma unroll
        for (int g = 0; g < 4; g++)
          acc[g] = __builtin_amdgcn_mfma_f32_16x16x32_bf16(au[ki].v, W[g][ki], acc[g], 0, 0, 0);
      }
    }
    // combine K-halves through LDS
    if (kh == 1) {
#pragma unroll
      for (int g = 0; g < 4; g++) lacc[hct][lane][g] = acc[g];
    }
    __syncthreads();
    if (kh == 0) {
#pragma unroll
      for (int g = 0; g < 4; g++) acc[g] += lacc[hct][lane][g];
      const long xbase = (long)slot * SLOT_XG;
#pragma unroll
      for (int r = 0; r < 4; r++) {
        const long row = rbase + lg * 4 + r;
        const long xr = xbase + row * 2048;
        const int colh = hc0 + lr;
        float gi = acc[0][r] + bf2f(xg[xr + colh]);
        float gf = acc[1][r] + bf2f(xg[xr + 512 + colh]);
        float gg = acc[2][r] + bf2f(xg[xr + 1024 + colh]);
        float go = acc[3][r] + bf2f(xg[xr + 1536 + colh]);
        float cn = sigm(gf) * creg[r] + sigm(gi) * tnh(gg);
        creg[r] = cn;
        stA_u16(&ho[row * hstride + colh], f2bf(sigm(go) * tnh(cn)));
      }
    }
    __syncthreads();  // vmcnt(0) drained: all h stores complete at coherence pt
    if (tid == 0) {
      __hip_atomic_fetch_add(cnt, 1u, __ATOMIC_RELAXED, __HIP_MEMORY_SCOPE_AGENT);
      if (ts != p.CH - 1) {
        const u32 tgt = 8u * (u32)(S + 1);
        while (__hip_atomic_load(cnt, __ATOMIC_RELAXED, __HIP_MEMORY_SCOPE_AGENT) < tgt)
          __builtin_amdgcn_s_sleep(1);
      }
    }
    __syncthreads();
  }
  if (kh == 0) {
#pragma unroll
    for (int r = 0; r < 4; r++)
      cbuf[(long)(rbase + lg * 4 + r) * 512 + hc0 + lr] = creg[r];
  }
}

// ---------------------------------------------------------------------------
// Embedding gathers -> bf16, TIME-MAJOR output (row = t*256 + b).
// ---------------------------------------------------------------------------
__global__ __launch_bounds__(256) void embed_enc_k(
    const int* __restrict__ q, const int* __restrict__ a, const int* __restrict__ pos,
    const int* __restrict__ fmt, const float* __restrict__ tw, const float* __restrict__ aw,
    const float* __restrict__ pw, const float* __restrict__ fw, u16* __restrict__ out) {
  const long blk = blockIdx.x;  // t*256 + b
  const int t = (int)(blk >> 8), b = (int)(blk & 255);
  const long src = (long)b * 256 + t;  // inputs are [B][T]
  const int iq = q[src], ia = a[src], ip = pos[src], ifm = fmt[src];
  for (int col = threadIdx.x; col < 288; col += 256) {
    float v;
    if (col < 128)      v = tw[(long)iq * 128 + col];
    else if (col < 256) v = aw[(long)ia * 128 + (col - 128)];
    else if (col < 272) v = pw[(long)ip * 16 + (col - 256)];
    else                v = fw[(long)ifm * 16 + (col - 272)];
    out[blk * 288 + col] = f2bf(v);
  }
}

__global__ __launch_bounds__(256) void embed_dec_k(
    const int* __restrict__ q, const int* __restrict__ a, const int* __restrict__ pos,
    const int* __restrict__ fmt, const int* __restrict__ last_a,
    const float* __restrict__ tw, const float* __restrict__ aw,
    const float* __restrict__ pw, const float* __restrict__ fw, u16* __restrict__ out) {
  const long blk = blockIdx.x;  // t*256 + b
  const int t = (int)(blk >> 8), b = (int)(blk & 255);
  const long src = (long)b * 256 + t;
  const int iq = q[src], ip = pos[src], ifm = fmt[src];
  const int pa = (t == 0) ? last_a[b] : a[src - 1];  // teacher forcing shift
  for (int col = threadIdx.x; col < 288; col += 256) {
    float v;
    if (col < 128)      v = tw[(long)iq * 128 + col];
    else if (col < 144) v = pw[(long)ip * 16 + (col - 128)];
    else if (col < 160) v = fw[(long)ifm * 16 + (col - 144)];
    else                v = aw[(long)pa * 128 + (col - 160)];
    out[blk * 288 + col] = f2bf(v);
  }
}

// out[b*256 + t0 + tl] = sigmoid(hidden[row] . w2 + b2); row = tl*256 + b.
__global__ __launch_bounds__(256) void pred_out_k(
    const u16* __restrict__ hidden, const float* __restrict__ w2,
    const float* __restrict__ b2, float* __restrict__ out, int t0) {
  const long r = (long)blockIdx.x * 4 + (threadIdx.x >> 6);
  const int lane = threadIdx.x & 63;
  const u16* hp = hidden + r * 512 + lane * 8;
  const float* wp = w2 + lane * 8;
  float s = 0.f;
#pragma unroll
  for (int j = 0; j < 8; j++) s += bf2f(hp[j]) * wp[j];
  for (int off = 32; off > 0; off >>= 1) s += __shfl_down(s, off);
  if (lane == 0) out[(r & 255) * 256 + t0 + (r >> 8)] = sigm(s + b2[0]);
}

__global__ __launch_bounds__(256) void conv_bf16_k(const float* __restrict__ s,
                                                   u16* __restrict__ d, long n) {
  long i = (long)blockIdx.x * 256 + threadIdx.x;
  if (i < n) d[i] = f2bf(s[i]);
}
__global__ __launch_bounds__(256) void bias_sum_k(const float* __restrict__ a,
                                                  const float* __restrict__ b,
                                                  float* __restrict__ d, int n) {
  int i = blockIdx.x * 256 + threadIdx.x;
  if (i < n) d[i] = a[i] + b[i];
}
__global__ __launch_bounds__(256) void zero_k(u32* __restrict__ p, int n) {
  int i = blockIdx.x * 256 + threadIdx.x;
  if (i < n) p[i] = 0;
}

// ---------------------------------------------------------------------------
extern "C" void kernel_launch(void* const* d_in, const int* in_sizes, int n_in,
                              void* d_out, int out_size, void* d_ws, size_t ws_size,
                              hipStream_t stream) {
  const int* enc_q     = (const int*)d_in[0];
  const int* enc_a     = (const int*)d_in[1];
  const int* enc_pos   = (const int*)d_in[2];
  const int* enc_fmt   = (const int*)d_in[3];
  const int* dec_q     = (const int*)d_in[4];
  const int* dec_a     = (const int*)d_in[5];
  const int* dec_pos   = (const int*)d_in[6];
  const int* dec_fmt   = (const int*)d_in[7];
  const int* enc_last  = (const int*)d_in[8];
  const float* t_emb   = (const float*)d_in[9];
  const float* a_emb   = (const float*)d_in[10];
  const float* pos_emb = (const float*)d_in[11];
  const float* fmt_emb = (const float*)d_in[12];
  const float* bif_w_ih = (const float*)d_in[13];
  const float* bif_w_hh = (const float*)d_in[14];
  const float* bif_b_ih = (const float*)d_in[15];
  const float* bif_b_hh = (const float*)d_in[16];
  const float* bib_w_ih = (const float*)d_in[17];
  const float* bib_w_hh = (const float*)d_in[18];
  const float* bib_b_ih = (const float*)d_in[19];
  const float* bib_b_hh = (const float*)d_in[20];
  const float* enc_w_ih = (const float*)d_in[21];
  const float* enc_w_hh = (const float*)d_in[22];
  const float* enc_b_ih = (const float*)d_in[23];
  const float* enc_b_hh = (const float*)d_in[24];
  const float* dec_w_ih = (const float*)d_in[25];
  const float* dec_w_hh = (const float*)d_in[26];
  const float* dec_b_ih = (const float*)d_in[27];
  const float* dec_b_hh = (const float*)d_in[28];
  const float* pred_w1 = (const float*)d_in[29];
  const float* pred_b1 = (const float*)d_in[30];
  const float* pred_w2 = (const float*)d_in[31];
  const float* pred_b2 = (const float*)d_in[32];
  (void)in_sizes; (void)n_in; (void)out_size;

  char* base = (char*)d_ws;
  size_t off = 0;
  auto alloc = [&](size_t bytes) -> char* {
    char* p = base + off;
    off = (off + bytes + 255) & ~(size_t)255;
    return p;
  };

  // --- fixed region ---
  u16* wb_bif_ih = (u16*)alloc(2048L * 288 * 2);
  u16* wb_bib_ih = (u16*)alloc(2048L * 288 * 2);
  u16* wb_enc_ih = (u16*)alloc(2048L * 1024 * 2);
  u16* wb_dec_ih = (u16*)alloc(2048L * 288 * 2);
  u16* wb_bif_hh = (u16*)alloc(2048L * 512 * 2);
  u16* wb_bib_hh = (u16*)alloc(2048L * 512 * 2);
  u16* wb_enc_hh = (u16*)alloc(2048L * 512 * 2);
  u16* wb_dec_hh = (u16*)alloc(2048L * 512 * 2);
  u16* wb_pred1  = (u16*)alloc(512L * 672 * 2);
  float* bias_bif = (float*)alloc(2048 * 4);
  float* bias_bib = (float*)alloc(2048 * 4);
  float* bias_enc = (float*)alloc(2048 * 4);
  float* bias_dec = (float*)alloc(2048 * 4);
  float* c_bif = (float*)alloc(256L * 512 * 4);
  float* c_bib = (float*)alloc(256L * 512 * 4);
  float* c_enc = (float*)alloc(256L * 512 * 4);
  u16* h_enc0 = (u16*)alloc(256L * 512 * 2);
  u16* h_enc1 = (u16*)alloc(256L * 512 * 2);
  u32* cnt = (u32*)alloc(64L * 32 * 4);  // 64 group counters, 128B stride

  // --- big activations (time-major) ---
  u16* bi    = (u16*)alloc(65536L * 1024 * 2);
  u16* dec_x = (u16*)alloc(65536L * 288 * 2);
  u16* enc_x = (u16*)alloc(65536L * 288 * 2);  // dead after phase 1 -> reuse

  int CH = 64;
  while (CH > 4 && off + 2ull * CH * 256 * 2048 * 2 > ws_size) CH >>= 1;
  u16* X1 = (u16*)alloc((size_t)CH * 256 * 2048 * 2);
  u16* X2 = (u16*)alloc((size_t)CH * 256 * 2048 * 2);
  u16* decout = enc_x;                         // CH-slot ring [CH][256][512]
  u16* hidden = enc_x + (long)CH * 256 * 512;  // [CH*256][512]
  const int NCH = 256 / CH;

  zero_k<<<8, 256, 0, stream>>>(cnt, 64 * 32);  // counters must start at 0

  auto CV = [&](const float* s, u16* d, long n) {
    conv_bf16_k<<<dim3((unsigned)((n + 255) / 256)), dim3(256), 0, stream>>>(s, d, n);
  };
  CV(bif_w_ih, wb_bif_ih, 2048L * 288);
  CV(bib_w_ih, wb_bib_ih, 2048L * 288);
  CV(enc_w_ih, wb_enc_ih, 2048L * 1024);
  CV(dec_w_ih, wb_dec_ih, 2048L * 288);
  CV(bif_w_hh, wb_bif_hh, 2048L * 512);
  CV(bib_w_hh, wb_bib_hh, 2048L * 512);
  CV(enc_w_hh, wb_enc_hh, 2048L * 512);
  CV(dec_w_hh, wb_dec_hh, 2048L * 512);
  CV(pred_w1, wb_pred1, 512L * 672);
  bias_sum_k<<<8, 256, 0, stream>>>(bif_b_ih, bif_b_hh, bias_bif, 2048);
  bias_sum_k<<<8, 256, 0, stream>>>(bib_b_ih, bib_b_hh, bias_bib, 2048);
  bias_sum_k<<<8, 256, 0, stream>>>(enc_b_ih, enc_b_hh, bias_enc, 2048);
  bias_sum_k<<<8, 256, 0, stream>>>(dec_b_ih, dec_b_hh, bias_dec, 2048);

  embed_enc_k<<<65536, 256, 0, stream>>>(enc_q, enc_a, enc_pos, enc_fmt,
                                         t_emb, a_emb, pos_emb, fmt_emb, enc_x);
  embed_dec_k<<<65536, 256, 0, stream>>>(dec_q, dec_a, dec_pos, dec_fmt, enc_last,
                                         t_emb, a_emb, pos_emb, fmt_emb, dec_x);

  // ---- phase 1: bif (fwd) + bib (bwd) persistent chunks -> bi ----
  for (int k = 0; k < NCH; k++) {
    const int t0f = k * CH;
    const int t0b = 256 - (k + 1) * CH;
    gemm_k<0><<<dim3(32, CH * 4), 256, 0, stream>>>(
        enc_x + (long)t0f * 256 * 288, 288, enc_x, 288, 288,
        wb_bif_ih, 288, bias_bif, X1, 2048, 288);
    gemm_k<0><<<dim3(32, CH * 4), 256, 0, stream>>>(
        enc_x + (long)t0b * 256 * 288, 288, enc_x, 288, 288,
        wb_bib_ih, 288, bias_bib, X2, 2048, 288);
    SeqP sp{X1, X2, wb_bif_hh, wb_bib_hh, c_bif, c_bib,
            bi, nullptr, nullptr, cnt, k, CH};
    lstm_seq_k<0><<<dim3(256), dim3(512), 0, stream>>>(sp);
  }

  // ---- phase 2: enc LSTM persistent chunks (final state only) ----
  for (int k = 0; k < NCH; k++) {
    const int t0 = k * CH;
    gemm_k<0><<<dim3(32, CH * 4), 256, 0, stream>>>(
        bi + (long)t0 * SLOT_BI, 1024, bi, 1024, 1024,
        wb_enc_ih, 1024, bias_enc, X1, 2048, 1024);
    SeqP sp{X1, nullptr, wb_enc_hh, nullptr, c_enc, nullptr,
            nullptr, h_enc0, h_enc1, cnt + 32L * 32, k, CH};
    lstm_seq_k<1><<<dim3(128), dim3(512), 0, stream>>>(sp);
  }
  // final h in h_enc0 (t=255 odd -> ho = h0), final c in c_enc

  // ---- phase 3: dec LSTM persistent chunks + per-chunk head ----
  for (int k = 0; k < NCH; k++) {
    const int t0 = k * CH;
    gemm_k<0><<<dim3(32, CH * 4), 256, 0, stream>>>(
        dec_x + (long)t0 * 256 * 288, 288, dec_x, 288, 288,
        wb_dec_ih, 288, bias_dec, X1, 2048, 288);
    SeqP sp{X1, nullptr, wb_dec_hh, nullptr, c_enc, nullptr,
            decout, h_enc0, nullptr, cnt + 48L * 32, k, CH};
    lstm_seq_k<2><<<dim3(128), dim3(512), 0, stream>>>(sp);
    gemm_k<1><<<dim3(8, CH * 4), 256, 0, stream>>>(
        dec_x + (long)t0 * 256 * 288, 288, decout, 512, 160,
        wb_pred1, 672, pred_b1, hidden, 512, 672);
    pred_out_k<<<CH * 64, 256, 0, stream>>>(hidden, pred_w2, pred_b2, (float*)d_out, t0);
  }
}

// Round 8
// 8416.877 us; speedup vs baseline: 1.7309x; 1.1305x over previous
//
#include <hip/hip_runtime.h>

// ---------------------------------------------------------------------------
// SDKT model: embeddings -> biLSTM encoder -> enc LSTM -> dec LSTM -> MLP head
// B=256, T=256, H=512, G=2048, enc/dec input = 288, enc2 input = 1024.
// GEMMs bf16 MFMA (f32 accum), K-loop FULLY UNROLLED via template (load
// pipelining; r7's runtime-K loop was latency-bound at 141 TF).
// Recurrences: persistent chunk kernels as REGULAR dispatches (grid <= 256
// blocks, all resident). w_hh register-resident; c register-resident per
// chunk; xg gate loads hoisted to step start (overlap with h-MFMA).
// Cross-block h exchange via relaxed AGENT-scope atomics (fence-free).
// Per-step scoped 8-block barrier via agent-scope atomic counter.
// Activations TIME-MAJOR [T][B][*].
// ---------------------------------------------------------------------------

using u16 = unsigned short;
using u32 = unsigned int;
using u64 = unsigned long long;
typedef float f32x4 __attribute__((ext_vector_type(4)));
typedef __bf16 bf16x8 __attribute__((ext_vector_type(8)));

__device__ __forceinline__ u16 f2bf(float f) {
  u32 u = __float_as_uint(f);
  u = (u + 0x7FFFu + ((u >> 16) & 1u)) >> 16;  // RNE
  return (u16)u;
}
__device__ __forceinline__ float bf2f(u16 h) { return __uint_as_float(((u32)h) << 16); }
__device__ __forceinline__ float sigm(float x) { return 1.f / (1.f + __expf(-x)); }
__device__ __forceinline__ float tnh(float x) {
  float a = fabsf(x), e = __expf(-2.f * a);
  float t = (1.f - e) / (1.f + e);
  return x < 0.f ? -t : t;
}

// agent-coherent primitives for cross-XCD h exchange (no fences needed)
__device__ __forceinline__ u64 ldA_u64(const u16* p) {
  return __hip_atomic_load((const u64*)p, __ATOMIC_RELAXED, __HIP_MEMORY_SCOPE_AGENT);
}
__device__ __forceinline__ void stA_u16(u16* p, u16 v) {
  __hip_atomic_store(p, v, __ATOMIC_RELAXED, __HIP_MEMORY_SCOPE_AGENT);
}

static const long SLOT_BI = 256L * 1024;  // one timestep of bi
static const long SLOT_DO = 256L * 512;   // one timestep of decout ring
static const long SLOT_XG = 256L * 2048;  // one timestep of xg

// ---------------------------------------------------------------------------
// bf16 MFMA GEMM: C[M,N] = act(A[M,K] @ W[N,K]^T + bias[N]); K = KITER*32,
// K-loop fully unrolled so the compiler pipelines the loads. A split at
// ksplit across two sources. 64x64 tile, 4 waves.
// ---------------------------------------------------------------------------
template <int ACT, int KITER>
__global__ __launch_bounds__(256) void gemm_k(
    const u16* __restrict__ A1, long lda1, const u16* __restrict__ A2, long lda2, int ksplit,
    const u16* __restrict__ W, long ldw, const float* __restrict__ bias,
    u16* __restrict__ C, long ldc) {
  const int lane = threadIdx.x & 63;
  const int wv = threadIdx.x >> 6;
  const int lr = lane & 15, lg = lane >> 4;
  const long mbase = (long)blockIdx.y * 64 + (wv >> 1) * 32;
  const long nbase = (long)blockIdx.x * 64 + (wv & 1) * 32;
  f32x4 acc[2][2] = {};
#pragma unroll
  for (int ki = 0; ki < KITER; ki++) {
    const int k0 = ki * 32 + lg * 8;
    bf16x8 a[2], b[2];
#pragma unroll
    for (int fm = 0; fm < 2; fm++) {
      const long row = mbase + fm * 16 + lr;
      const u16* p = (k0 < ksplit) ? (A1 + row * lda1 + k0)
                                   : (A2 + row * lda2 + (k0 - ksplit));
      a[fm] = *reinterpret_cast<const bf16x8*>(p);
    }
#pragma unroll
    for (int fn = 0; fn < 2; fn++) {
      const long col = nbase + fn * 16 + lr;
      b[fn] = *reinterpret_cast<const bf16x8*>(W + col * ldw + k0);
    }
#pragma unroll
    for (int fm = 0; fm < 2; fm++)
#pragma unroll
      for (int fn = 0; fn < 2; fn++)
        acc[fm][fn] = __builtin_amdgcn_mfma_f32_16x16x32_bf16(a[fm], b[fn], acc[fm][fn], 0, 0, 0);
  }
#pragma unroll
  for (int fm = 0; fm < 2; fm++)
#pragma unroll
    for (int fn = 0; fn < 2; fn++)
#pragma unroll
      for (int r = 0; r < 4; r++) {
        const long row = mbase + fm * 16 + lg * 4 + r;  // C/D: row=(lane>>4)*4+reg
        const long col = nbase + fn * 16 + lr;          //      col=lane&15
        float v = acc[fm][fn][r] + bias[col];
        if (ACT == 1) v = tnh(v);
        C[row * ldc + col] = f2bf(v);
      }
}

// ---------------------------------------------------------------------------
// Persistent chunk LSTM (r4/r7-proven). MODE 0: biLSTM (2 dirs, history = bi,
// stride 1024). MODE 1: enc (ping-pong h0/h1). MODE 2: dec (ring histA, init
// h0, c continues). Block = 512 thr = 8 waves = 4 hcol-tiles x 2 khalves;
// 16 rows x 64 hcols. Group = 8 blocks. W in regs, c in regs per chunk.
// xg loads hoisted to step start (no in-step dependency) to overlap latency.
// ---------------------------------------------------------------------------
struct SeqP {
  const u16 *xgA, *xgB;
  const u16 *whA, *whB;
  float *cA, *cB;
  u16 *histA;        // MODE0: bi; MODE2: decout ring
  u16 *h0, *h1;      // MODE1: ping-pong; MODE2: h0 = initial h (h_enc0)
  u32 *cnt;          // per-group counters, stride 32 u32 (128B)
  int k, CH;
};

template <int MODE>
__global__ __launch_bounds__(512, 2) void lstm_seq_k(SeqP p) {
  const int tid = threadIdx.x;
  const int w = tid >> 6, lane = tid & 63, lr = lane & 15, lg = lane >> 4;
  const int hct = w & 3, kh = w >> 2;
  int dir, rt, kb;
  if (MODE == 0) { dir = blockIdx.x >> 7; rt = (blockIdx.x >> 3) & 15; kb = blockIdx.x & 7; }
  else           { dir = 0;               rt = blockIdx.x >> 3;        kb = blockIdx.x & 7; }
  const u16* xg = (MODE == 0 && dir) ? p.xgB : p.xgA;
  const u16* wh = (MODE == 0 && dir) ? p.whB : p.whA;
  float* cbuf   = (MODE == 0 && dir) ? p.cB  : p.cA;
  const int rbase = rt * 16;
  const int hc0 = kb * 64 + hct * 16;
  const int kofs = kh * 256;
  u32* cnt = p.cnt + (long)((MODE == 0) ? (dir * 16 + rt) : rt) * 32;

  // --- resident weights: 4 gates x 8 k-iters, bf16x8 each ---
  bf16x8 W[4][8];
#pragma unroll
  for (int g = 0; g < 4; g++)
#pragma unroll
    for (int ki = 0; ki < 8; ki++)
      W[g][ki] = *reinterpret_cast<const bf16x8*>(
          wh + (long)(g * 512 + hc0 + lr) * 512 + kofs + ki * 32 + lg * 8);

  // --- resident cell state (kh0 waves use it) ---
  const bool zero_init = (MODE <= 1) && (p.k == 0);
  float creg[4];
#pragma unroll
  for (int r = 0; r < 4; r++) {
    creg[r] = 0.f;
    if (kh == 0 && !zero_init)
      creg[r] = cbuf[(long)(rbase + lg * 4 + r) * 512 + hc0 + lr];
  }

  __shared__ f32x4 lacc[4][64][4];  // [hct][lane][gate]  (16 KB)

  for (int ts = 0; ts < p.CH; ts++) {
    const int S = p.k * p.CH + ts;  // phase-global step index
    const u16* hp;
    u16* ho;
    long hstride;
    int slot;
    bool first;
    if (MODE == 0) {
      const int t = dir == 0 ? S : 255 - S;
      slot = dir == 0 ? ts : p.CH - 1 - ts;
      hstride = 1024;
      const int tp = dir == 0 ? t - 1 : t + 1;
      hp = p.histA + (long)tp * SLOT_BI + dir * 512;
      ho = p.histA + (long)t * SLOT_BI + dir * 512;
      first = (S == 0);
    } else if (MODE == 1) {
      slot = ts; hstride = 512;
      hp = (S & 1) ? p.h1 : p.h0;
      ho = (S & 1) ? p.h0 : p.h1;
      first = (S == 0);
    } else {
      slot = ts; hstride = 512;
      hp = (S == 0) ? p.h0 : p.histA + (long)((S - 1) & (p.CH - 1)) * SLOT_DO;
      ho = p.histA + (long)(S & (p.CH - 1)) * SLOT_DO;
      first = false;
    }

    // ---- hoisted xg gate loads (no in-step dependency; overlap with MFMA) ---
    u16 xv[4][4];
    if (kh == 0) {
      const long xbase = (long)slot * SLOT_XG;
      const int colh = hc0 + lr;
#pragma unroll
      for (int r = 0; r < 4; r++) {
        const long xr = xbase + (long)(rbase + lg * 4 + r) * 2048 + colh;
#pragma unroll
        for (int g = 0; g < 4; g++) xv[r][g] = xg[xr + g * 512];
      }
    }

    f32x4 acc[4] = {};
    if (!first) {
      // issue ALL h loads (agent-coherent) before any use -> pipelined
      union AU { u64 q[2]; bf16x8 v; } au[8];
      const u16* abase = hp + (long)(rbase + lr) * hstride + kofs;
#pragma unroll
      for (int ki = 0; ki < 8; ki++) {
        au[ki].q[0] = ldA_u64(abase + ki * 32 + lg * 8);
        au[ki].q[1] = ldA_u64(abase + ki * 32 + lg * 8 + 4);
      }
#pragma unroll
      for (int ki = 0; ki < 8; ki++) {
#pragma unroll
        for (int g = 0; g < 4; g++)
          acc[g] = __builtin_amdgcn_mfma_f32_16x16x32_bf16(au[ki].v, W[g][ki], acc[g], 0, 0, 0);
      }
    }
    // combine K-halves through LDS
    if (kh == 1) {
#pragma unroll
      for (int g = 0; g < 4; g++) lacc[hct][lane][g] = acc[g];
    }
    __syncthreads();
    if (kh == 0) {
#pragma unroll
      for (int g = 0; g < 4; g++) acc[g] += lacc[hct][lane][g];
#pragma unroll
      for (int r = 0; r < 4; r++) {
        const long row = rbase + lg * 4 + r;
        const int colh = hc0 + lr;
        float gi = acc[0][r] + bf2f(xv[r][0]);
        float gf = acc[1][r] + bf2f(xv[r][1]);
        float gg = acc[2][r] + bf2f(xv[r][2]);
        float go = acc[3][r] + bf2f(xv[r][3]);
        float cn = sigm(gf) * creg[r] + sigm(gi) * tnh(gg);
        creg[r] = cn;
        stA_u16(&ho[row * hstride + colh], f2bf(sigm(go) * tnh(cn)));
      }
    }
    __syncthreads();  // vmcnt(0) drained: all h stores complete at coherence pt
    if (tid == 0) {
      __hip_atomic_fetch_add(cnt, 1u, __ATOMIC_RELAXED, __HIP_MEMORY_SCOPE_AGENT);
      if (ts != p.CH - 1) {
        const u32 tgt = 8u * (u32)(S + 1);
        while (__hip_atomic_load(cnt, __ATOMIC_RELAXED, __HIP_MEMORY_SCOPE_AGENT) < tgt)
          __builtin_amdgcn_s_sleep(1);
      }
    }
    __syncthreads();
  }
  if (kh == 0) {
#pragma unroll
    for (int r = 0; r < 4; r++)
      cbuf[(long)(rbase + lg * 4 + r) * 512 + hc0 + lr] = creg[r];
  }
}

// ---------------------------------------------------------------------------
// Embedding gathers -> bf16, TIME-MAJOR output (row = t*256 + b).
// ---------------------------------------------------------------------------
__global__ __launch_bounds__(256) void embed_enc_k(
    const int* __restrict__ q, const int* __restrict__ a, const int* __restrict__ pos,
    const int* __restrict__ fmt, const float* __restrict__ tw, const float* __restrict__ aw,
    const float* __restrict__ pw, const float* __restrict__ fw, u16* __restrict__ out) {
  const long blk = blockIdx.x;  // t*256 + b
  const int t = (int)(blk >> 8), b = (int)(blk & 255);
  const long src = (long)b * 256 + t;  // inputs are [B][T]
  const int iq = q[src], ia = a[src], ip = pos[src], ifm = fmt[src];
  for (int col = threadIdx.x; col < 288; col += 256) {
    float v;
    if (col < 128)      v = tw[(long)iq * 128 + col];
    else if (col < 256) v = aw[(long)ia * 128 + (col - 128)];
    else if (col < 272) v = pw[(long)ip * 16 + (col - 256)];
    else                v = fw[(long)ifm * 16 + (col - 272)];
    out[blk * 288 + col] = f2bf(v);
  }
}

__global__ __launch_bounds__(256) void embed_dec_k(
    const int* __restrict__ q, const int* __restrict__ a, const int* __restrict__ pos,
    const int* __restrict__ fmt, const int* __restrict__ last_a,
    const float* __restrict__ tw, const float* __restrict__ aw,
    const float* __restrict__ pw, const float* __restrict__ fw, u16* __restrict__ out) {
  const long blk = blockIdx.x;  // t*256 + b
  const int t = (int)(blk >> 8), b = (int)(blk & 255);
  const long src = (long)b * 256 + t;
  const int iq = q[src], ip = pos[src], ifm = fmt[src];
  const int pa = (t == 0) ? last_a[b] : a[src - 1];  // teacher forcing shift
  for (int col = threadIdx.x; col < 288; col += 256) {
    float v;
    if (col < 128)      v = tw[(long)iq * 128 + col];
    else if (col < 144) v = pw[(long)ip * 16 + (col - 128)];
    else if (col < 160) v = fw[(long)ifm * 16 + (col - 144)];
    else                v = aw[(long)pa * 128 + (col - 160)];
    out[blk * 288 + col] = f2bf(v);
  }
}

// out[b*256 + t0 + tl] = sigmoid(hidden[row] . w2 + b2); row = tl*256 + b.
__global__ __launch_bounds__(256) void pred_out_k(
    const u16* __restrict__ hidden, const float* __restrict__ w2,
    const float* __restrict__ b2, float* __restrict__ out, int t0) {
  const long r = (long)blockIdx.x * 4 + (threadIdx.x >> 6);
  const int lane = threadIdx.x & 63;
  const u16* hp = hidden + r * 512 + lane * 8;
  const float* wp = w2 + lane * 8;
  float s = 0.f;
#pragma unroll
  for (int j = 0; j < 8; j++) s += bf2f(hp[j]) * wp[j];
  for (int off = 32; off > 0; off >>= 1) s += __shfl_down(s, off);
  if (lane == 0) out[(r & 255) * 256 + t0 + (r >> 8)] = sigm(s + b2[0]);
}

__global__ __launch_bounds__(256) void conv_bf16_k(const float* __restrict__ s,
                                                   u16* __restrict__ d, long n) {
  long i = (long)blockIdx.x * 256 + threadIdx.x;
  if (i < n) d[i] = f2bf(s[i]);
}
__global__ __launch_bounds__(256) void bias_sum_k(const float* __restrict__ a,
                                                  const float* __restrict__ b,
                                                  float* __restrict__ d, int n) {
  int i = blockIdx.x * 256 + threadIdx.x;
  if (i < n) d[i] = a[i] + b[i];
}
__global__ __launch_bounds__(256) void zero_k(u32* __restrict__ p, int n) {
  int i = blockIdx.x * 256 + threadIdx.x;
  if (i < n) p[i] = 0;
}

// ---------------------------------------------------------------------------
extern "C" void kernel_launch(void* const* d_in, const int* in_sizes, int n_in,
                              void* d_out, int out_size, void* d_ws, size_t ws_size,
                              hipStream_t stream) {
  const int* enc_q     = (const int*)d_in[0];
  const int* enc_a     = (const int*)d_in[1];
  const int* enc_pos   = (const int*)d_in[2];
  const int* enc_fmt   = (const int*)d_in[3];
  const int* dec_q     = (const int*)d_in[4];
  const int* dec_a     = (const int*)d_in[5];
  const int* dec_pos   = (const int*)d_in[6];
  const int* dec_fmt   = (const int*)d_in[7];
  const int* enc_last  = (const int*)d_in[8];
  const float* t_emb   = (const float*)d_in[9];
  const float* a_emb   = (const float*)d_in[10];
  const float* pos_emb = (const float*)d_in[11];
  const float* fmt_emb = (const float*)d_in[12];
  const float* bif_w_ih = (const float*)d_in[13];
  const float* bif_w_hh = (const float*)d_in[14];
  const float* bif_b_ih = (const float*)d_in[15];
  const float* bif_b_hh = (const float*)d_in[16];
  const float* bib_w_ih = (const float*)d_in[17];
  const float* bib_w_hh = (const float*)d_in[18];
  const float* bib_b_ih = (const float*)d_in[19];
  const float* bib_b_hh = (const float*)d_in[20];
  const float* enc_w_ih = (const float*)d_in[21];
  const float* enc_w_hh = (const float*)d_in[22];
  const float* enc_b_ih = (const float*)d_in[23];
  const float* enc_b_hh = (const float*)d_in[24];
  const float* dec_w_ih = (const float*)d_in[25];
  const float* dec_w_hh = (const float*)d_in[26];
  const float* dec_b_ih = (const float*)d_in[27];
  const float* dec_b_hh = (const float*)d_in[28];
  const float* pred_w1 = (const float*)d_in[29];
  const float* pred_b1 = (const float*)d_in[30];
  const float* pred_w2 = (const float*)d_in[31];
  const float* pred_b2 = (const float*)d_in[32];
  (void)in_sizes; (void)n_in; (void)out_size;

  char* base = (char*)d_ws;
  size_t off = 0;
  auto alloc = [&](size_t bytes) -> char* {
    char* p = base + off;
    off = (off + bytes + 255) & ~(size_t)255;
    return p;
  };

  // --- fixed region ---
  u16* wb_bif_ih = (u16*)alloc(2048L * 288 * 2);
  u16* wb_bib_ih = (u16*)alloc(2048L * 288 * 2);
  u16* wb_enc_ih = (u16*)alloc(2048L * 1024 * 2);
  u16* wb_dec_ih = (u16*)alloc(2048L * 288 * 2);
  u16* wb_bif_hh = (u16*)alloc(2048L * 512 * 2);
  u16* wb_bib_hh = (u16*)alloc(2048L * 512 * 2);
  u16* wb_enc_hh = (u16*)alloc(2048L * 512 * 2);
  u16* wb_dec_hh = (u16*)alloc(2048L * 512 * 2);
  u16* wb_pred1  = (u16*)alloc(512L * 672 * 2);
  float* bias_bif = (float*)alloc(2048 * 4);
  float* bias_bib = (float*)alloc(2048 * 4);
  float* bias_enc = (float*)alloc(2048 * 4);
  float* bias_dec = (float*)alloc(2048 * 4);
  float* c_bif = (float*)alloc(256L * 512 * 4);
  float* c_bib = (float*)alloc(256L * 512 * 4);
  float* c_enc = (float*)alloc(256L * 512 * 4);
  u16* h_enc0 = (u16*)alloc(256L * 512 * 2);
  u16* h_enc1 = (u16*)alloc(256L * 512 * 2);
  u32* cnt = (u32*)alloc(64L * 32 * 4);  // 64 group counters, 128B stride

  // --- big activations (time-major) ---
  u16* bi    = (u16*)alloc(65536L * 1024 * 2);
  u16* dec_x = (u16*)alloc(65536L * 288 * 2);
  u16* enc_x = (u16*)alloc(65536L * 288 * 2);  // dead after phase 1 -> reuse

  int CH = 64;
  while (CH > 4 && off + 2ull * CH * 256 * 2048 * 2 > ws_size) CH >>= 1;
  u16* X1 = (u16*)alloc((size_t)CH * 256 * 2048 * 2);
  u16* X2 = (u16*)alloc((size_t)CH * 256 * 2048 * 2);
  u16* decout = enc_x;                         // CH-slot ring [CH][256][512]
  u16* hidden = enc_x + (long)CH * 256 * 512;  // [CH*256][512]
  const int NCH = 256 / CH;

  zero_k<<<8, 256, 0, stream>>>(cnt, 64 * 32);  // counters must start at 0

  auto CV = [&](const float* s, u16* d, long n) {
    conv_bf16_k<<<dim3((unsigned)((n + 255) / 256)), dim3(256), 0, stream>>>(s, d, n);
  };
  CV(bif_w_ih, wb_bif_ih, 2048L * 288);
  CV(bib_w_ih, wb_bib_ih, 2048L * 288);
  CV(enc_w_ih, wb_enc_ih, 2048L * 1024);
  CV(dec_w_ih, wb_dec_ih, 2048L * 288);
  CV(bif_w_hh, wb_bif_hh, 2048L * 512);
  CV(bib_w_hh, wb_bib_hh, 2048L * 512);
  CV(enc_w_hh, wb_enc_hh, 2048L * 512);
  CV(dec_w_hh, wb_dec_hh, 2048L * 512);
  CV(pred_w1, wb_pred1, 512L * 672);
  bias_sum_k<<<8, 256, 0, stream>>>(bif_b_ih, bif_b_hh, bias_bif, 2048);
  bias_sum_k<<<8, 256, 0, stream>>>(bib_b_ih, bib_b_hh, bias_bib, 2048);
  bias_sum_k<<<8, 256, 0, stream>>>(enc_b_ih, enc_b_hh, bias_enc, 2048);
  bias_sum_k<<<8, 256, 0, stream>>>(dec_b_ih, dec_b_hh, bias_dec, 2048);

  embed_enc_k<<<65536, 256, 0, stream>>>(enc_q, enc_a, enc_pos, enc_fmt,
                                         t_emb, a_emb, pos_emb, fmt_emb, enc_x);
  embed_dec_k<<<65536, 256, 0, stream>>>(dec_q, dec_a, dec_pos, dec_fmt, enc_last,
                                         t_emb, a_emb, pos_emb, fmt_emb, dec_x);

  // ---- phase 1: bif (fwd) + bib (bwd) persistent chunks -> bi ----
  for (int k = 0; k < NCH; k++) {
    const int t0f = k * CH;
    const int t0b = 256 - (k + 1) * CH;
    gemm_k<0, 9><<<dim3(32, CH * 4), 256, 0, stream>>>(
        enc_x + (long)t0f * 256 * 288, 288, enc_x, 288, 288,
        wb_bif_ih, 288, bias_bif, X1, 2048);
    gemm_k<0, 9><<<dim3(32, CH * 4), 256, 0, stream>>>(
        enc_x + (long)t0b * 256 * 288, 288, enc_x, 288, 288,
        wb_bib_ih, 288, bias_bib, X2, 2048);
    SeqP sp{X1, X2, wb_bif_hh, wb_bib_hh, c_bif, c_bib,
            bi, nullptr, nullptr, cnt, k, CH};
    lstm_seq_k<0><<<dim3(256), dim3(512), 0, stream>>>(sp);
  }

  // ---- phase 2: enc LSTM persistent chunks (final state only) ----
  for (int k = 0; k < NCH; k++) {
    const int t0 = k * CH;
    gemm_k<0, 32><<<dim3(32, CH * 4), 256, 0, stream>>>(
        bi + (long)t0 * SLOT_BI, 1024, bi, 1024, 1024,
        wb_enc_ih, 1024, bias_enc, X1, 2048);
    SeqP sp{X1, nullptr, wb_enc_hh, nullptr, c_enc, nullptr,
            nullptr, h_enc0, h_enc1, cnt + 32L * 32, k, CH};
    lstm_seq_k<1><<<dim3(128), dim3(512), 0, stream>>>(sp);
  }
  // final h in h_enc0 (t=255 odd -> ho = h0), final c in c_enc

  // ---- phase 3: dec LSTM persistent chunks + per-chunk head ----
  for (int k = 0; k < NCH; k++) {
    const int t0 = k * CH;
    gemm_k<0, 9><<<dim3(32, CH * 4), 256, 0, stream>>>(
        dec_x + (long)t0 * 256 * 288, 288, dec_x, 288, 288,
        wb_dec_ih, 288, bias_dec, X1, 2048);
    SeqP sp{X1, nullptr, wb_dec_hh, nullptr, c_enc, nullptr,
            decout, h_enc0, nullptr, cnt + 48L * 32, k, CH};
    lstm_seq_k<2><<<dim3(128), dim3(512), 0, stream>>>(sp);
    gemm_k<1, 21><<<dim3(8, CH * 4), 256, 0, stream>>>(
        dec_x + (long)t0 * 256 * 288, 288, decout, 512, 160,
        wb_pred1, 672, pred_b1, hidden, 512);
    pred_out_k<<<CH * 64, 256, 0, stream>>>(hidden, pred_w2, pred_b2, (float*)d_out, t0);
  }
}